// Round 6
// baseline (1134.903 us; speedup 1.0000x reference)
//
#include <hip/hip_runtime.h>

// ---------- types ----------
typedef __attribute__((ext_vector_type(8))) short short8;   // 8 bf16 (4 VGPR)
typedef __attribute__((ext_vector_type(4))) float f32x4;    // MFMA accumulator

__device__ __forceinline__ unsigned short f2bf(float f) {
    unsigned u = __float_as_uint(f);
    u += 0x7fffu + ((u >> 16) & 1u);   // RNE
    return (unsigned short)(u >> 16);
}
__device__ __forceinline__ float bf2f(unsigned short s) {
    return __uint_as_float((unsigned)s << 16);
}

// hex neighbor tables (y is 0-based row inside 11x15 grid)
__device__ const int g_DY[7]  = {-1, -1, 0, 0, 0, 1, 1};
__device__ const int g_DXO[7] = { 0,  1, -1, 0, 1, 0, 1};   // y odd
__device__ const int g_DXE[7] = {-1,  0, -1, 0, 1, -1, 0};  // y even

// ---------- prep: x fp32 -> bf16 ----------
__global__ void __launch_bounds__(256) cvt_x_kernel(const float* __restrict__ in,
                                                    unsigned short* __restrict__ out,
                                                    int n8) {
    int stride = gridDim.x * blockDim.x;
    for (int i = blockIdx.x * blockDim.x + threadIdx.x; i < n8; i += stride) {
        const float4* p = reinterpret_cast<const float4*>(in) + (size_t)i * 2;
        float4 a = p[0], b = p[1];
        short8 o;
        o[0] = (short)f2bf(a.x); o[1] = (short)f2bf(a.y);
        o[2] = (short)f2bf(a.z); o[3] = (short)f2bf(a.w);
        o[4] = (short)f2bf(b.x); o[5] = (short)f2bf(b.y);
        o[6] = (short)f2bf(b.z); o[7] = (short)f2bf(b.w);
        *reinterpret_cast<short8*>(out + (size_t)i * 8) = o;
    }
}

// ---------- prep: W (1792x256 f32) -> Wt (256x1792 bf16), transposed ----------
__global__ void __launch_bounds__(256) cvt_wt_kernel(const float* __restrict__ W1,
                                                     const float* __restrict__ W2,
                                                     unsigned short* __restrict__ W1t,
                                                     unsigned short* __restrict__ W2t) {
    const float* W = blockIdx.z ? W2 : W1;
    unsigned short* Wt = blockIdx.z ? W2t : W1t;
    int k0 = blockIdx.x * 64;
    int n0 = blockIdx.y * 64;
    __shared__ float tile[64][65];
    for (int e = threadIdx.x; e < 4096; e += 256) {
        int r = e >> 6, c = e & 63;
        tile[r][c] = W[(size_t)(k0 + r) * 256 + n0 + c];
    }
    __syncthreads();
    for (int e = threadIdx.x; e < 4096; e += 256) {
        int r = e >> 6, c = e & 63;
        Wt[(size_t)(n0 + r) * 1792 + k0 + c] = f2bf(tile[c][r]);
    }
}

// ---------- barrier-free register-direct hex-conv GEMM ----------
// Block = 256 thr = 4 m-waves; tile M=256 (64 rows/wave), N=64.
// Grid 2640 = 660 m-tiles x 4 n-tiles.  No LDS in K-loop, no barriers:
// A and B fragments loaded global->VGPR.  A: per-lane hex-gather addressing.
// B: all 4 waves read identical addresses -> L1 broadcast, L2-resident.
// Frag maps (validated rounds 1-5 via LDS equivalents):
//   A: lane holds row (l&15) of frag, k-chunk (l>>4)*8 within 32-k step
//   B: lane holds col (l&15),        k-chunk (l>>4)*8
//   C: col = l&15, row = (l>>4)*4 + r
// MODE 0: out bf16 (leaky(acc+bias));  MODE 1: out fp32 leaky(acc+bias+resid)
template <int MODE>
__global__ void __launch_bounds__(256) hexconv_reg_kernel(
        const unsigned short* __restrict__ xg,      // (B*165, 256) bf16
        const unsigned short* __restrict__ wt,      // (256, 1792) bf16 Wt[n][k]
        const float* __restrict__ bias,             // (256,)
        const unsigned short* __restrict__ residbf, // (B*165,256) bf16 or null
        void* __restrict__ outp,
        const unsigned short* __restrict__ zp)      // 512B zero page
{
    __shared__ float tlds[4 * 64 * 68];             // per-wave epilogue transpose

    const int t = threadIdx.x;
    const int lane = t & 63, w = t >> 6;
    const int l15 = lane & 15, lhi = lane >> 4;

    // XCD swizzle (2640 = 8*330), n fastest within an XCD chunk
    int bid = blockIdx.x;
    int gl = (bid & 7) * 330 + (bid >> 3);
    const int mb = gl >> 2, nb = gl & 3;

    // ---- per-frag per-lane A row geometry ----
    int yv[4], xv[4], browv[4];
#pragma unroll
    for (int f = 0; f < 4; ++f) {
        int m = mb * 256 + w * 64 + f * 16 + l15;
        int b = m / 165;
        int i = m - b * 165;
        int y = i / 15;
        int x = i - y * 15;
        yv[f] = y; xv[f] = x; browv[f] = m - i;     // b*165
    }

    // ---- B base pointers (constant over K; identical across the 4 waves) ----
    const unsigned short* bbase[4];
#pragma unroll
    for (int f = 0; f < 4; ++f)
        bbase[f] = wt + (size_t)(nb * 64 + f * 16 + l15) * 1792 + lhi * 8;

    f32x4 acc[4][4];
#pragma unroll
    for (int f = 0; f < 4; ++f)
#pragma unroll
        for (int g = 0; g < 4; ++g) {
            f32x4 z = {0.f, 0.f, 0.f, 0.f};
            acc[f][g] = z;
        }

    const unsigned short* abase[2][4];
    short8 ab[3][4], bb[2][4];

    // compute A base pointers for neighbor j into set SET (per-lane gather)
#define SET_ABASE(SET, J) do {                                                \
        const int dy_ = g_DY[J], dxo_ = g_DXO[J], dxe_ = g_DXE[J];            \
        _Pragma("unroll")                                                     \
        for (int f = 0; f < 4; ++f) {                                         \
            int dx_ = (yv[f] & 1) ? dxo_ : dxe_;                              \
            int ny_ = yv[f] + dy_, nx_ = xv[f] + dx_;                         \
            bool v_ = ((unsigned)ny_ < 11u) && ((unsigned)nx_ < 15u);         \
            abase[SET][f] = v_ ? (xg + (size_t)(browv[f] + ny_ * 15 + nx_) * 256 + lhi * 8) \
                               : zp;                                          \
        } } while (0)

    // A load: in-j step S (0..7), offset S*32 elems (imm-folds)
#define LOADA(DST, SET, S) do { _Pragma("unroll")                             \
        for (int f = 0; f < 4; ++f)                                           \
            DST[f] = *(const short8*)(abase[SET][f] + (S) * 32); } while (0)
    // B load: flat step SS (0..55), offset SS*64 B (imm-folds, max 3520)
#define LOADB(DST, SS) do { _Pragma("unroll")                                 \
        for (int f = 0; f < 4; ++f)                                           \
            DST[f] = *(const short8*)(bbase[f] + (SS) * 32); } while (0)

#define STEP(AB, BB) do { _Pragma("unroll")                                   \
        for (int f = 0; f < 4; ++f) _Pragma("unroll")                         \
        for (int g = 0; g < 4; ++g)                                           \
            acc[f][g] = __builtin_amdgcn_mfma_f32_16x16x32_bf16(              \
                AB[f], BB[g], acc[f][g], 0, 0, 0); } while (0)

    // ---- prologue: 2-step A lookahead, 1-step B ----
    SET_ABASE(0, 0);
    LOADA(ab[0], 0, 0);
    LOADA(ab[1], 0, 1);
    LOADB(bb[0], 0);

    // ---- flat 56-step K loop (7 neighbors x 8 steps of 32k), fully unrolled ----
#pragma unroll
    for (int ss = 0; ss < 56; ++ss) {
        const int pa = ss + 2, pj = pa >> 3, ps = pa & 7;
        if (pa < 56) {
            if (ps == 0) SET_ABASE(pj & 1, pj);
            LOADA(ab[pa % 3], pj & 1, ps);
        }
        if (ss + 1 < 56) LOADB(bb[(ss + 1) & 1], ss + 1);
        STEP(ab[ss % 3], bb[ss & 1]);
    }

    // ---- epilogue: per-wave LDS transpose -> full-line coalesced stores ----
    float* my = tlds + w * (64 * 68);
#pragma unroll
    for (int g = 0; g < 4; ++g) {
        float bz = bias[nb * 64 + g * 16 + l15];
#pragma unroll
        for (int f = 0; f < 4; ++f)
#pragma unroll
            for (int r = 0; r < 4; ++r) {
                float v = acc[f][g][r] + bz;
                if (MODE == 0) v = v > 0.f ? v : 0.01f * v;   // leaky before store
                my[(f * 16 + lhi * 4 + r) * 68 + g * 16 + l15] = v;
            }
    }
    __syncthreads();
    const int rrow = lane >> 3, rc8 = (lane & 7) * 8;
#pragma unroll
    for (int rr = 0; rr < 8; ++rr) {
        int row = rr * 8 + rrow;
        float4 v0 = *(float4*)&my[row * 68 + rc8];
        float4 v1 = *(float4*)&my[row * 68 + rc8 + 4];
        size_t gm = (size_t)mb * 256 + w * 64 + row;
        int gc = nb * 64 + rc8;
        if (MODE == 0) {
            unsigned short* outh = (unsigned short*)outp;
            short8 o;
            o[0] = (short)f2bf(v0.x); o[1] = (short)f2bf(v0.y);
            o[2] = (short)f2bf(v0.z); o[3] = (short)f2bf(v0.w);
            o[4] = (short)f2bf(v1.x); o[5] = (short)f2bf(v1.y);
            o[6] = (short)f2bf(v1.z); o[7] = (short)f2bf(v1.w);
            *(short8*)&outh[gm * 256 + gc] = o;
        } else {
            float* outf = (float*)outp;
            short8 rv = *(const short8*)&residbf[gm * 256 + gc];
            float4 w0, w1;
            w0.x = v0.x + bf2f((unsigned short)rv[0]);
            w0.y = v0.y + bf2f((unsigned short)rv[1]);
            w0.z = v0.z + bf2f((unsigned short)rv[2]);
            w0.w = v0.w + bf2f((unsigned short)rv[3]);
            w1.x = v1.x + bf2f((unsigned short)rv[4]);
            w1.y = v1.y + bf2f((unsigned short)rv[5]);
            w1.z = v1.z + bf2f((unsigned short)rv[6]);
            w1.w = v1.w + bf2f((unsigned short)rv[7]);
            w0.x = w0.x > 0.f ? w0.x : 0.01f * w0.x;
            w0.y = w0.y > 0.f ? w0.y : 0.01f * w0.y;
            w0.z = w0.z > 0.f ? w0.z : 0.01f * w0.z;
            w0.w = w0.w > 0.f ? w0.w : 0.01f * w0.w;
            w1.x = w1.x > 0.f ? w1.x : 0.01f * w1.x;
            w1.y = w1.y > 0.f ? w1.y : 0.01f * w1.y;
            w1.z = w1.z > 0.f ? w1.z : 0.01f * w1.z;
            w1.w = w1.w > 0.f ? w1.w : 0.01f * w1.w;
            *(float4*)&outf[gm * 256 + gc] = w0;
            *(float4*)&outf[gm * 256 + gc + 4] = w1;
        }
    }
}

// ---------- launcher ----------
extern "C" void kernel_launch(void* const* d_in, const int* in_sizes, int n_in,
                              void* d_out, int out_size, void* d_ws, size_t ws_size,
                              hipStream_t stream) {
    const float* x  = (const float*)d_in[0];
    const float* W1 = (const float*)d_in[1];
    const float* b1 = (const float*)d_in[2];
    const float* W2 = (const float*)d_in[3];
    const float* b2 = (const float*)d_in[4];
    float* out = (float*)d_out;

    const size_t XBF = (size_t)1024 * 165 * 256 * 2;  // 86,507,520 B
    const size_t WTB = (size_t)256 * 1792 * 2;        //    917,504 B
    char* ws = (char*)d_ws;
    unsigned short* zp  = (unsigned short*)ws;               // 512 B zero page
    unsigned short* xbf = (unsigned short*)(ws + 512);
    unsigned short* hbf = (unsigned short*)(ws + 512 + XBF);
    unsigned short* w1t = (unsigned short*)(ws + 512 + 2 * XBF);
    unsigned short* w2t = (unsigned short*)(ws + 512 + 2 * XBF + WTB);

    hipMemsetAsync(d_ws, 0, 512, stream);
    cvt_x_kernel<<<2048, 256, 0, stream>>>(x, xbf, 5406720);
    cvt_wt_kernel<<<dim3(28, 4, 2), 256, 0, stream>>>(W1, W2, w1t, w2t);
    hexconv_reg_kernel<0><<<2640, 256, 0, stream>>>(xbf, w1t, b1, nullptr, (void*)hbf, zp);
    hexconv_reg_kernel<1><<<2640, 256, 0, stream>>>(hbf, w2t, b2, xbf, (void*)out, zp);
}

// Round 7
// 500.438 us; speedup vs baseline: 2.2678x; 2.2678x over previous
//
#include <hip/hip_runtime.h>

// ---------- types ----------
typedef __attribute__((ext_vector_type(8))) short short8;   // 8 bf16 (4 VGPR)
typedef __attribute__((ext_vector_type(4))) float f32x4;    // MFMA accumulator

typedef __attribute__((address_space(1))) const unsigned int guint;
typedef __attribute__((address_space(3))) unsigned int luint;

__device__ __forceinline__ void gload16(const void* g, void* l) {
    __builtin_amdgcn_global_load_lds((guint*)g, (luint*)l, 16, 0, 0);
}

__device__ __forceinline__ unsigned short f2bf(float f) {
    unsigned u = __float_as_uint(f);
    u += 0x7fffu + ((u >> 16) & 1u);   // RNE
    return (unsigned short)(u >> 16);
}
__device__ __forceinline__ float bf2f(unsigned short s) {
    return __uint_as_float((unsigned)s << 16);
}

// ---------- prep: x fp32 -> bf16 ----------
__global__ void __launch_bounds__(256) cvt_x_kernel(const float* __restrict__ in,
                                                    unsigned short* __restrict__ out,
                                                    int n8) {
    int stride = gridDim.x * blockDim.x;
    for (int i = blockIdx.x * blockDim.x + threadIdx.x; i < n8; i += stride) {
        const float4* p = reinterpret_cast<const float4*>(in) + (size_t)i * 2;
        float4 a = p[0], b = p[1];
        short8 o;
        o[0] = (short)f2bf(a.x); o[1] = (short)f2bf(a.y);
        o[2] = (short)f2bf(a.z); o[3] = (short)f2bf(a.w);
        o[4] = (short)f2bf(b.x); o[5] = (short)f2bf(b.y);
        o[6] = (short)f2bf(b.z); o[7] = (short)f2bf(b.w);
        *reinterpret_cast<short8*>(out + (size_t)i * 8) = o;
    }
}

// ---------- prep: W (1792x256 f32) -> Wt (256x1792 bf16), transposed ----------
__global__ void __launch_bounds__(256) cvt_wt_kernel(const float* __restrict__ W1,
                                                     const float* __restrict__ W2,
                                                     unsigned short* __restrict__ W1t,
                                                     unsigned short* __restrict__ W2t) {
    const float* W = blockIdx.z ? W2 : W1;
    unsigned short* Wt = blockIdx.z ? W2t : W1t;
    int k0 = blockIdx.x * 64;
    int n0 = blockIdx.y * 64;
    __shared__ float tile[64][65];
    for (int e = threadIdx.x; e < 4096; e += 256) {
        int r = e >> 6, c = e & 63;
        tile[r][c] = W[(size_t)(k0 + r) * 256 + n0 + c];
    }
    __syncthreads();
    for (int e = threadIdx.x; e < 4096; e += 256) {
        int r = e >> 6, c = e & 63;
        Wt[(size_t)(n0 + r) * 1792 + k0 + c] = f2bf(tile[c][r]);
    }
}

// ---------- merged-phase 256x256 hex-conv GEMM ----------
// 2 phases per K-tile (32 MFMA each), ONE barrier per phase.
// Staging of tile t+1 (all 8 loads, issued at PhA head, FIFO order
// B0..B3,A0,A2,A1,A3):
//   PhA-close: vmcnt(8) -> drains prev tile's A1,A3 (PhB reads them)
//   PhB-close: vmcnt(2) -> drains B0..B3,A0,A2 (next PhA reads them),
//              leaves A1',A3' in flight across the tile boundary.
// Hazards: staging->read licensed by counted vmcnt + closing BAR;
// read->overwrite by previous phase's closing BAR (reads complete at lgkm0).
// MODE 0: out bf16 (LDS-transposed full-line stores);  MODE 1: fp32 + resid
template <int MODE>
__global__ void __launch_bounds__(512, 2) hexconv8_kernel(
        const unsigned short* __restrict__ xg,      // (B*165, 256) bf16
        const unsigned short* __restrict__ wt,      // (256, 1792) bf16 Wt[n][k]
        const float* __restrict__ bias,             // (256,)
        const unsigned short* __restrict__ residbf, // (B*165,256) bf16 or null
        void* __restrict__ outp,
        const unsigned short* __restrict__ zp)      // 256B zero page
{
    // LDS: [buf p][A 256x64 | B 256x64] bf16, double buffered = 128 KiB
    __shared__ unsigned short smem[65536];

    const int t = threadIdx.x;
    const int lane = t & 63, w = t >> 6;
    const int wr = w >> 2, wc = w & 3;   // 2M x 4N waves, per-wave 128x64

    // bijective XCD swizzle for grid 660 (q=82, r=4)
    int bid = blockIdx.x;
    int xcd = bid & 7, idx = bid >> 3;
    const int mb = (xcd < 4 ? xcd * 83 : 332 + (xcd - 4) * 82) + idx;

    // ---- staging precompute (512 thr; each owns 4 A-rows + 4 B-rows) ----
    const int trow = t >> 3;             // 0..63
    const int chunk = t & 7;
    const int aswz = (chunk ^ (trow & 7)) * 8;   // inverse-swizzled 16B chunk (elems)
    int yv[4], xv[4], brow[4], aoff[4];
    const unsigned short* wsrcp[4];
#pragma unroll
    for (int i = 0; i < 4; ++i) {
        int row = i * 64 + trow;                 // tile-local row (A: m-row, B: n-row)
        int m = mb * 256 + row;
        int b = m / 165;
        int ii = m - b * 165;
        int y = ii / 15;
        int x = ii - y * 15;
        yv[i] = y; xv[i] = x; brow[i] = m - ii;  // b*165
        wsrcp[i] = wt + (size_t)row * 1792 + aswz;
    }

    // neighbor tables bit-packed ((val+1) in 2 bits per j) -> no memory loads
    // DY=[-1,-1,0,0,0,1,1]->10576  DXO=[0,1,-1,0,1,0,1]->9801
    // DXE=[-1,0,-1,0,1,-1,0]->4676
#define CALC_AOFF(J) do {                                                     \
        int dy_  = ((10576 >> (2 * (J))) & 3) - 1;                            \
        int dxo_ = ((9801  >> (2 * (J))) & 3) - 1;                            \
        int dxe_ = ((4676  >> (2 * (J))) & 3) - 1;                            \
        _Pragma("unroll")                                                     \
        for (int i = 0; i < 4; ++i) {                                         \
            int dx_ = (yv[i] & 1) ? dxo_ : dxe_;                              \
            int ny_ = yv[i] + dy_, nx_ = xv[i] + dx_;                         \
            bool v_ = ((unsigned)ny_ < 11u) && ((unsigned)nx_ < 15u);         \
            aoff[i] = v_ ? ((brow[i] + ny_ * 15 + nx_) * 256 + aswz) : -1;    \
        } } while (0)

    // ---- ds_read fragment offsets (shorts, within one buffer) ----
    int offA[4][2], offB[2][2][2];
    {
        int l15 = lane & 15, lhi = lane >> 4, l7 = lane & 7;
#pragma unroll
        for (int f = 0; f < 4; ++f)
#pragma unroll
            for (int ks = 0; ks < 2; ++ks)
                offA[f][ks] = (wr * 128 + f * 16 + l15) * 64 + (((ks * 4 + lhi) ^ l7) * 8);
#pragma unroll
        for (int nh = 0; nh < 2; ++nh)
#pragma unroll
            for (int g = 0; g < 2; ++g)
#pragma unroll
                for (int ks = 0; ks < 2; ++ks)
                    offB[nh][g][ks] = (wc * 64 + nh * 32 + g * 16 + l15) * 64 +
                                      (((ks * 4 + lhi) ^ l7) * 8);
    }

    f32x4 acc[8][4];
#pragma unroll
    for (int mf = 0; mf < 8; ++mf)
#pragma unroll
        for (int nf = 0; nf < 4; ++nf) {
            f32x4 z = {0.f, 0.f, 0.f, 0.f};
            acc[mf][nf] = z;
        }
    short8 a[4][2], b0[2][2], b1[2][2];

#define STAGE_A_ONE(I, TT, Q) do { int c0_ = ((TT) & 3) * 64;                 \
        const unsigned short* g_ = (aoff[I] >= 0) ? (xg + aoff[I] + c0_) : zp; \
        gload16(g_, &smem[(Q) * 32768 + (I) * 4096 + t * 8]); } while (0)
#define STAGE_B_ALL(TT, Q) do { int ko_ = (TT) * 64;                          \
        _Pragma("unroll")                                                     \
        for (int i = 0; i < 4; ++i)                                           \
            gload16(wsrcp[i] + ko_, &smem[(Q) * 32768 + 16384 + i * 4096 + t * 8]); \
        } while (0)

#define LDA(P, MH) do { _Pragma("unroll") for (int f = 0; f < 4; ++f)         \
        _Pragma("unroll") for (int ks = 0; ks < 2; ++ks)                      \
            a[f][ks] = *(const short8*)&smem[(P) * 32768 + (MH) * 4096 + offA[f][ks]]; \
        } while (0)
#define LDB(P, NH, DST) do { _Pragma("unroll") for (int g = 0; g < 2; ++g)    \
        _Pragma("unroll") for (int ks = 0; ks < 2; ++ks)                      \
            DST[g][ks] = *(const short8*)&smem[(P) * 32768 + 16384 + offB[NH][g][ks]]; \
        } while (0)

#define QUAD(MH, NH, BF) do { _Pragma("unroll") for (int f = 0; f < 4; ++f)   \
        _Pragma("unroll") for (int g = 0; g < 2; ++g)                         \
        _Pragma("unroll") for (int ks = 0; ks < 2; ++ks)                      \
            acc[(MH) * 4 + f][(NH) * 2 + g] = __builtin_amdgcn_mfma_f32_16x16x32_bf16( \
                a[f][ks], BF[g][ks], acc[(MH) * 4 + f][(NH) * 2 + g], 0, 0, 0); \
        } while (0)

#define BAR() __builtin_amdgcn_s_barrier()
#define LGKM0() do { asm volatile("s_waitcnt lgkmcnt(0)" ::: "memory");       \
                     __builtin_amdgcn_sched_barrier(0); } while (0)
#define VMCNT(N) do { asm volatile("s_waitcnt vmcnt(" #N ")" ::: "memory");   \
                      __builtin_amdgcn_sched_barrier(0); } while (0)
#define PRIO(N) __builtin_amdgcn_s_setprio(N)

#define TILE2(T28, P) do {                                                    \
        int tt_ = (T28) + 1;                                                  \
        bool st_ = (tt_ < 28);                                                \
        /* PhA: stage all 8 for tile t+1; compute MH=0 x full N */            \
        if (st_) {                                                            \
            if ((tt_ & 3) == 0) CALC_AOFF(tt_ >> 2);                          \
            STAGE_B_ALL(tt_, 1 - (P));                                        \
            STAGE_A_ONE(0, tt_, 1 - (P));                                     \
            STAGE_A_ONE(2, tt_, 1 - (P));                                     \
            STAGE_A_ONE(1, tt_, 1 - (P));                                     \
            STAGE_A_ONE(3, tt_, 1 - (P));                                     \
        }                                                                     \
        LDA(P, 0); LDB(P, 0, b0); LDB(P, 1, b1);                              \
        LGKM0(); PRIO(1); QUAD(0, 0, b0); QUAD(0, 1, b1); PRIO(0);            \
        if (st_) { VMCNT(8); } else { VMCNT(0); } /* drain prev A1,A3 */      \
        BAR();                                                                \
        /* PhB: compute MH=1 x full N */                                      \
        LDA(P, 1);                                                            \
        LGKM0(); PRIO(1); QUAD(1, 1, b1); QUAD(1, 0, b0); PRIO(0);            \
        if (st_) { VMCNT(2); } else { VMCNT(0); } /* drain B',A0',A2' */      \
        BAR();                                                                \
    } while (0)

    // ---- prologue: stage tile 0 fully, drain, sync ----
    CALC_AOFF(0);
    STAGE_B_ALL(0, 0);
    STAGE_A_ONE(0, 0, 0); STAGE_A_ONE(2, 0, 0);
    STAGE_A_ONE(1, 0, 0); STAGE_A_ONE(3, 0, 0);
    VMCNT(0); BAR();

#pragma unroll 1
    for (int it = 0; it < 14; ++it) {
        TILE2(2 * it, 0);
        TILE2(2 * it + 1, 1);
    }

    // ---- epilogue ----
    const size_t mrowbase = (size_t)mb * 256 + wr * 128;
    const int l15 = lane & 15, lhi = lane >> 4;
    if (MODE == 0) {
        // LDS-transposed bf16 stores: full 128B-per-wave lines, no RMW.
        unsigned short* outh = (unsigned short*)outp;
        unsigned short* my = smem + w * (64 * 68);
#pragma unroll 1
        for (int h = 0; h < 2; ++h) {
            __syncthreads();
#pragma unroll
            for (int mf2 = 0; mf2 < 4; ++mf2) {
#pragma unroll
                for (int nf = 0; nf < 4; ++nf) {
                    float bb = bias[wc * 64 + nf * 16 + l15];
#pragma unroll
                    for (int r = 0; r < 4; ++r) {
                        float v = acc[h * 4 + mf2][nf][r] + bb;
                        v = v > 0.f ? v : 0.01f * v;
                        my[(mf2 * 16 + lhi * 4 + r) * 68 + nf * 16 + l15] = f2bf(v);
                    }
                }
            }
            __syncthreads();
#pragma unroll
            for (int rr = 0; rr < 8; ++rr) {
                int row = rr * 8 + (lane >> 3);
                short8 vv = *(const short8*)&my[row * 68 + (lane & 7) * 8];
                size_t gm = mrowbase + h * 64 + row;
                *(short8*)&outh[gm * 256 + wc * 64 + (lane & 7) * 8] = vv;
            }
        }
    } else {
        float* outf = (float*)outp;
#pragma unroll
        for (int nf = 0; nf < 4; ++nf) {
            int col = wc * 64 + nf * 16 + l15;
            float bb = bias[col];
#pragma unroll
            for (int mf = 0; mf < 8; ++mf)
#pragma unroll
                for (int r = 0; r < 4; ++r) {
                    size_t mr = mrowbase + mf * 16 + lhi * 4 + r;
                    float v = acc[mf][nf][r] + bb + bf2f(residbf[mr * 256 + col]);
                    v = v > 0.f ? v : 0.01f * v;
                    outf[mr * 256 + col] = v;
                }
        }
    }
}

// ---------- launcher ----------
extern "C" void kernel_launch(void* const* d_in, const int* in_sizes, int n_in,
                              void* d_out, int out_size, void* d_ws, size_t ws_size,
                              hipStream_t stream) {
    const float* x  = (const float*)d_in[0];
    const float* W1 = (const float*)d_in[1];
    const float* b1 = (const float*)d_in[2];
    const float* W2 = (const float*)d_in[3];
    const float* b2 = (const float*)d_in[4];
    float* out = (float*)d_out;

    const size_t XBF = (size_t)1024 * 165 * 256 * 2;  // 86,507,520 B
    const size_t WTB = (size_t)256 * 1792 * 2;        //    917,504 B
    char* ws = (char*)d_ws;
    unsigned short* zp  = (unsigned short*)ws;               // 256 B zero page
    unsigned short* xbf = (unsigned short*)(ws + 256);
    unsigned short* hbf = (unsigned short*)(ws + 256 + XBF);
    unsigned short* w1t = (unsigned short*)(ws + 256 + 2 * XBF);
    unsigned short* w2t = (unsigned short*)(ws + 256 + 2 * XBF + WTB);

    hipMemsetAsync(d_ws, 0, 256, stream);
    cvt_x_kernel<<<2048, 256, 0, stream>>>(x, xbf, 5406720);
    cvt_wt_kernel<<<dim3(28, 4, 2), 256, 0, stream>>>(W1, W2, w1t, w2t);
    hexconv8_kernel<0><<<660, 512, 0, stream>>>(xbf, w1t, b1, nullptr, (void*)hbf, zp);
    hexconv8_kernel<1><<<660, 512, 0, stream>>>(hbf, w2t, b2, xbf, (void*)out, zp);
}

// Round 9
// 453.856 us; speedup vs baseline: 2.5006x; 1.1026x over previous
//
#include <hip/hip_runtime.h>

// ---------- types ----------
typedef __attribute__((ext_vector_type(8))) short short8;   // 8 bf16 (4 VGPR)
typedef __attribute__((ext_vector_type(4))) float f32x4;    // MFMA accumulator

typedef __attribute__((address_space(1))) const unsigned int guint;
typedef __attribute__((address_space(3))) unsigned int luint;

__device__ __forceinline__ void gload16(const void* g, void* l) {
    __builtin_amdgcn_global_load_lds((guint*)g, (luint*)l, 16, 0, 0);
}

__device__ __forceinline__ unsigned short f2bf(float f) {
    unsigned u = __float_as_uint(f);
    u += 0x7fffu + ((u >> 16) & 1u);   // RNE
    return (unsigned short)(u >> 16);
}
__device__ __forceinline__ float bf2f(unsigned short s) {
    return __uint_as_float((unsigned)s << 16);
}

// ---------- prep: x fp32 -> bf16 ----------
__global__ void __launch_bounds__(256) cvt_x_kernel(const float* __restrict__ in,
                                                    unsigned short* __restrict__ out,
                                                    int n8) {
    int stride = gridDim.x * blockDim.x;
    for (int i = blockIdx.x * blockDim.x + threadIdx.x; i < n8; i += stride) {
        const float4* p = reinterpret_cast<const float4*>(in) + (size_t)i * 2;
        float4 a = p[0], b = p[1];
        short8 o;
        o[0] = (short)f2bf(a.x); o[1] = (short)f2bf(a.y);
        o[2] = (short)f2bf(a.z); o[3] = (short)f2bf(a.w);
        o[4] = (short)f2bf(b.x); o[5] = (short)f2bf(b.y);
        o[6] = (short)f2bf(b.z); o[7] = (short)f2bf(b.w);
        *reinterpret_cast<short8*>(out + (size_t)i * 8) = o;
    }
}

// ---------- prep: W (1792x256 f32) -> Wt (256x1792 bf16), transposed ----------
__global__ void __launch_bounds__(256) cvt_wt_kernel(const float* __restrict__ W1,
                                                     const float* __restrict__ W2,
                                                     unsigned short* __restrict__ W1t,
                                                     unsigned short* __restrict__ W2t) {
    const float* W = blockIdx.z ? W2 : W1;
    unsigned short* Wt = blockIdx.z ? W2t : W1t;
    int k0 = blockIdx.x * 64;
    int n0 = blockIdx.y * 64;
    __shared__ float tile[64][65];
    for (int e = threadIdx.x; e < 4096; e += 256) {
        int r = e >> 6, c = e & 63;
        tile[r][c] = W[(size_t)(k0 + r) * 256 + n0 + c];
    }
    __syncthreads();
    for (int e = threadIdx.x; e < 4096; e += 256) {
        int r = e >> 6, c = e & 63;
        Wt[(size_t)(n0 + r) * 1792 + k0 + c] = f2bf(tile[c][r]);
    }
}

// ---------- 128x128 hex-conv GEMM, 2 blocks/CU ----------
// Block = 256 thr = 4 waves (1M x 4N); per-wave 128x32 output; BK=64.
// LDS 64 KiB (double-buffered 128x64 A + 128x64 B) -> 2 independent
// blocks/CU so stalls in one barrier group are filled by the other.
// Grid 2640 = 1320 m-tiles x 2 n-tiles (round-8 launched 1320: half the
// rows were never computed -- the absmax-5.34 bug).
// MODE 0: out bf16;  MODE 1: out fp32 + bf16 residual
template <int MODE>
__global__ void __launch_bounds__(256, 2) hexconv2_kernel(
        const unsigned short* __restrict__ xg,      // (B*165, 256) bf16
        const unsigned short* __restrict__ wt,      // (256, 1792) bf16 Wt[n][k]
        const float* __restrict__ bias,             // (256,)
        const unsigned short* __restrict__ residbf, // (B*165,256) bf16 or null
        void* __restrict__ outp,
        const unsigned short* __restrict__ zp)      // 256B zero page
{
    // LDS: [buf p][A 128x64 | B 128x64] bf16, double buffered = 64 KiB
    __shared__ unsigned short smem[32768];

    const int t = threadIdx.x;
    const int lane = t & 63, wc = t >> 6;    // 4 N-waves

    // XCD swizzle: 2640 = 8*330; nb fastest (A L2-sharing pairs)
    int bid = blockIdx.x;
    int gl = (bid & 7) * 330 + (bid >> 3);
    const int mb = gl >> 1, nb = gl & 1;     // mb in [0,1320)

    // ---- staging precompute (256 thr; 4 A-regions + 4 B-regions of 32 rows) ----
    const int trow = t >> 3;             // 0..31
    const int chunk = t & 7;
    const int aswz = (chunk ^ (trow & 7)) * 8;   // inverse-swizzled 16B chunk (elems)
    int yv[4], xv[4], brow[4], aoff[4];
    const unsigned short* wsrcp[4];
#pragma unroll
    for (int i = 0; i < 4; ++i) {
        int row = i * 32 + trow;                 // tile-local row
        int m = mb * 128 + row;
        int b = m / 165;
        int ii = m - b * 165;
        int y = ii / 15;
        int x = ii - y * 15;
        yv[i] = y; xv[i] = x; brow[i] = m - ii;  // b*165
        wsrcp[i] = wt + (size_t)(nb * 128 + row) * 1792 + aswz;
    }

    // neighbor tables bit-packed ((val+1) 2 bits/j): DY->10576 DXO->9801 DXE->4676
#define CALC_AOFF(J) do {                                                     \
        int dy_  = ((10576 >> (2 * (J))) & 3) - 1;                            \
        int dxo_ = ((9801  >> (2 * (J))) & 3) - 1;                            \
        int dxe_ = ((4676  >> (2 * (J))) & 3) - 1;                            \
        _Pragma("unroll")                                                     \
        for (int i = 0; i < 4; ++i) {                                         \
            int dx_ = (yv[i] & 1) ? dxo_ : dxe_;                              \
            int ny_ = yv[i] + dy_, nx_ = xv[i] + dx_;                         \
            bool v_ = ((unsigned)ny_ < 11u) && ((unsigned)nx_ < 15u);         \
            aoff[i] = v_ ? ((brow[i] + ny_ * 15 + nx_) * 256 + aswz) : -1;    \
        } } while (0)

    // ---- ds_read bases (f/g folded as compile-time immediates) ----
    int offA_e[2], offB_e[2];
    {
        int l15 = lane & 15, lhi = lane >> 4, l7 = lane & 7;
#pragma unroll
        for (int ks = 0; ks < 2; ++ks) {
            offA_e[ks] = l15 * 64 + (((ks * 4 + lhi) ^ l7) * 8);
            offB_e[ks] = (wc * 32 + l15) * 64 + (((ks * 4 + lhi) ^ l7) * 8);
        }
    }

    f32x4 acc[8][2];
#pragma unroll
    for (int mf = 0; mf < 8; ++mf)
#pragma unroll
        for (int nf = 0; nf < 2; ++nf) {
            f32x4 z = {0.f, 0.f, 0.f, 0.f};
            acc[mf][nf] = z;
        }
    short8 a[4][2], b[2][2];

#define STAGE_A_ALL(TT, Q) do { int c0_ = ((TT) & 3) * 64;                    \
        _Pragma("unroll")                                                     \
        for (int i = 0; i < 4; ++i) {                                         \
            const unsigned short* g_ = (aoff[i] >= 0) ? (xg + aoff[i] + c0_) : zp; \
            gload16(g_, &smem[(Q) * 16384 + i * 2048 + t * 8]);               \
        } } while (0)
#define STAGE_B_ALL(TT, Q) do { int ko_ = (TT) * 64;                          \
        _Pragma("unroll")                                                     \
        for (int i = 0; i < 4; ++i)                                           \
            gload16(wsrcp[i] + ko_, &smem[(Q) * 16384 + 8192 + i * 2048 + t * 8]); \
        } while (0)

    // MH half = A rows MH*64..+63 -> MH*4096 elems; f*16 rows = 1024 elems
#define LDA(P, MH) do { _Pragma("unroll") for (int f = 0; f < 4; ++f)         \
        _Pragma("unroll") for (int ks = 0; ks < 2; ++ks)                      \
            a[f][ks] = *(const short8*)&smem[(P) * 16384 + (MH) * 4096 +      \
                                             f * 1024 + offA_e[ks]];          \
        } while (0)
#define LDB(P) do { _Pragma("unroll") for (int g = 0; g < 2; ++g)             \
        _Pragma("unroll") for (int ks = 0; ks < 2; ++ks)                      \
            b[g][ks] = *(const short8*)&smem[(P) * 16384 + 8192 +             \
                                             g * 1024 + offB_e[ks]];          \
        } while (0)

#define QUAD(MH) do { _Pragma("unroll") for (int f = 0; f < 4; ++f)           \
        _Pragma("unroll") for (int g = 0; g < 2; ++g)                         \
        _Pragma("unroll") for (int ks = 0; ks < 2; ++ks)                      \
            acc[(MH) * 4 + f][g] = __builtin_amdgcn_mfma_f32_16x16x32_bf16(   \
                a[f][ks], b[g][ks], acc[(MH) * 4 + f][g], 0, 0, 0);           \
        } while (0)

#define BAR() __builtin_amdgcn_s_barrier()
#define LGKM0() do { asm volatile("s_waitcnt lgkmcnt(0)" ::: "memory");       \
                     __builtin_amdgcn_sched_barrier(0); } while (0)
#define VMCNT(N) do { asm volatile("s_waitcnt vmcnt(" #N ")" ::: "memory");   \
                      __builtin_amdgcn_sched_barrier(0); } while (0)
#define PRIO(N) __builtin_amdgcn_s_setprio(N)

#define TILE(T28, P) do {                                                     \
        int tt_ = (T28) + 1;                                                  \
        bool st_ = (tt_ < 28);                                                \
        /* SubA: stage A' ; compute MH=0 */                                   \
        if (st_) {                                                            \
            if ((tt_ & 3) == 0) CALC_AOFF(tt_ >> 2);                          \
            STAGE_A_ALL(tt_, 1 - (P));                                        \
        }                                                                     \
        LDA(P, 0); LDB(P);                                                    \
        BAR(); LGKM0(); PRIO(1); QUAD(0); PRIO(0); BAR();                     \
        /* SubB: stage B' ; compute MH=1 */                                   \
        if (st_) STAGE_B_ALL(tt_, 1 - (P));                                   \
        LDA(P, 1);                                                            \
        BAR(); LGKM0(); PRIO(1); QUAD(1); PRIO(0);                            \
        VMCNT(0); BAR();                                                      \
    } while (0)

    // ---- prologue: stage tile 0 fully, drain, sync ----
    CALC_AOFF(0);
    STAGE_A_ALL(0, 0);
    STAGE_B_ALL(0, 0);
    VMCNT(0); BAR();

#pragma unroll 1
    for (int it = 0; it < 14; ++it) {
        TILE(2 * it, 0);
        TILE(2 * it + 1, 1);
    }

    // ---- epilogue ----
    const size_t mrowbase = (size_t)mb * 128;
    const int l15 = lane & 15, lq = (lane >> 4) * 4;
    if (MODE == 0) {
        unsigned short* outh = (unsigned short*)outp;
#pragma unroll
        for (int nf = 0; nf < 2; ++nf) {
            int col = nb * 128 + wc * 32 + nf * 16 + l15;
            float bb = bias[col];
#pragma unroll
            for (int mf = 0; mf < 8; ++mf)
#pragma unroll
                for (int r = 0; r < 4; ++r) {
                    size_t mr = mrowbase + mf * 16 + lq + r;
                    float v = acc[mf][nf][r] + bb;
                    v = v > 0.f ? v : 0.01f * v;
                    outh[mr * 256 + col] = f2bf(v);
                }
        }
    } else {
        float* outf = (float*)outp;
#pragma unroll
        for (int nf = 0; nf < 2; ++nf) {
            int col = nb * 128 + wc * 32 + nf * 16 + l15;
            float bb = bias[col];
#pragma unroll
            for (int mf = 0; mf < 8; ++mf)
#pragma unroll
                for (int r = 0; r < 4; ++r) {
                    size_t mr = mrowbase + mf * 16 + lq + r;
                    float v = acc[mf][nf][r] + bb + bf2f(residbf[mr * 256 + col]);
                    v = v > 0.f ? v : 0.01f * v;
                    outf[mr * 256 + col] = v;
                }
        }
    }
}

// ---------- launcher ----------
extern "C" void kernel_launch(void* const* d_in, const int* in_sizes, int n_in,
                              void* d_out, int out_size, void* d_ws, size_t ws_size,
                              hipStream_t stream) {
    const float* x  = (const float*)d_in[0];
    const float* W1 = (const float*)d_in[1];
    const float* b1 = (const float*)d_in[2];
    const float* W2 = (const float*)d_in[3];
    const float* b2 = (const float*)d_in[4];
    float* out = (float*)d_out;

    const size_t XBF = (size_t)1024 * 165 * 256 * 2;  // 86,507,520 B
    const size_t WTB = (size_t)256 * 1792 * 2;        //    917,504 B
    char* ws = (char*)d_ws;
    unsigned short* zp  = (unsigned short*)ws;               // 256 B zero page
    unsigned short* xbf = (unsigned short*)(ws + 256);
    unsigned short* hbf = (unsigned short*)(ws + 256 + XBF);
    unsigned short* w1t = (unsigned short*)(ws + 256 + 2 * XBF);
    unsigned short* w2t = (unsigned short*)(ws + 256 + 2 * XBF + WTB);

    hipMemsetAsync(d_ws, 0, 256, stream);
    cvt_x_kernel<<<2048, 256, 0, stream>>>(x, xbf, 5406720);
    cvt_wt_kernel<<<dim3(28, 4, 2), 256, 0, stream>>>(W1, W2, w1t, w2t);
    hexconv2_kernel<0><<<2640, 256, 0, stream>>>(xbf, w1t, b1, nullptr, (void*)hbf, zp);
    hexconv2_kernel<1><<<2640, 256, 0, stream>>>(hbf, w2t, b2, xbf, (void*)out, zp);
}